// Round 1
// baseline (433.247 us; speedup 1.0000x reference)
//
#include <hip/hip_runtime.h>
#include <hip/hip_bf16.h>

// ---------------------------------------------------------------------------
// TT-linear = x_pad(8192x4096) @ W(4096x4096) + bias, with W precomputed from
// the 8 TT cores on device each call.
//   A-side:  A4[i=(d0 d1 d2 d3)][r4] = c0*c1*c2*c3 chain   (4096 x 64)
//   B-side:  B4[r4][j=(d4 d5 d6 d7)] = c4*c5*c6*c7 chain   (64 x 4096)
//   Wt[j][i] = sum_r A4[i][r] * B4[r][j]   (stored N x K, bf16)
// Main GEMM: m97-style 128x128x32 bf16 MFMA, global_load_lds staging.
// ---------------------------------------------------------------------------

typedef __attribute__((ext_vector_type(8))) short short8;
typedef __attribute__((ext_vector_type(4))) float f32x4;

__device__ __forceinline__ short f2bf(float f) {
    union { float f; unsigned u; } c; c.f = f;
    unsigned u = c.u;
    unsigned r = (u + 0x7fffu + ((u >> 16) & 1u)) >> 16;  // RNE
    return (short)r;
}

// ---------------- cast + pad x : (8192,4000) f32 -> (8192,4096) bf16 --------
__global__ __launch_bounds__(256) void cast_x_kernel(const float* __restrict__ x,
                                                     short* __restrict__ xb) {
    const int total = 8192 * 512;  // 16B output chunks (8 bf16 each)
    for (int c = blockIdx.x * 256 + threadIdx.x; c < total;
         c += gridDim.x * 256) {
        int row = c >> 9;
        int j0  = (c & 511) << 3;
        short8 v;
        if (j0 + 8 <= 4000) {
            const f32x4* p = (const f32x4*)(x + row * 4000 + j0);
            f32x4 a = p[0], b = p[1];
            v[0] = f2bf(a[0]); v[1] = f2bf(a[1]); v[2] = f2bf(a[2]); v[3] = f2bf(a[3]);
            v[4] = f2bf(b[0]); v[5] = f2bf(b[1]); v[6] = f2bf(b[2]); v[7] = f2bf(b[3]);
        } else {
#pragma unroll
            for (int u = 0; u < 8; ++u) {
                int j = j0 + u;
                float f = (j < 4000) ? x[row * 4000 + j] : 0.f;
                v[u] = f2bf(f);
            }
        }
        *(short8*)(xb + row * 4096 + j0) = v;
    }
}

// ---------------- A-side chain step ----------------------------------------
// out[(i*8+d)][s] = sum_r in[i][r] * core[(r*8+d)*64 + s]
// grid = Ni*8 blocks, 64 threads
__global__ void tt_a_step(const float* __restrict__ in,
                          const float* __restrict__ core,
                          float* __restrict__ out) {
    const int row = blockIdx.x;
    const int i = row >> 3, d = row & 7;
    const int s = threadIdx.x;
    float acc = 0.f;
    for (int r = 0; r < 64; ++r)
        acc += in[i * 64 + r] * core[(r * 8 + d) * 64 + s];
    out[row * 64 + s] = acc;
}

// ---------------- B-side chain step ----------------------------------------
// out[r][d*Wj + j] = sum_q core[(r*8+d)*64 + q] * in[q*Wj + j]
// grid = 512 blocks (r*8+d), 256 threads
__global__ void tt_b_step(const float* __restrict__ in,
                          const float* __restrict__ core,
                          float* __restrict__ out, int Wj) {
    const int rd = blockIdx.x;
    const int r = rd >> 3, d = rd & 7;
    for (int j = threadIdx.x; j < Wj; j += 256) {
        float acc = 0.f;
        for (int q = 0; q < 64; ++q)
            acc += core[(r * 8 + d) * 64 + q] * in[q * Wj + j];
        out[r * (8 * Wj) + d * Wj + j] = acc;
    }
}

// ---------------- Wt[j][i] = sum_r A4[i][r]*B4[r][j], bf16 ------------------
// grid = 64x64 = 4096 blocks of 256 threads; 64x64 output tile per block
__global__ __launch_bounds__(256) void build_wt_kernel(
    const float* __restrict__ A4, const float* __restrict__ B4,
    short* __restrict__ Wt) {
    __shared__ float Ast[64][65];  // [r][i] padded (+1) to dodge conflicts
    __shared__ float Bsm[64][64];  // [r][j]
    const int t = threadIdx.x;
    const int i0 = (blockIdx.x & 63) << 6;
    const int j0 = (blockIdx.x >> 6) << 6;
#pragma unroll 4
    for (int it = 0; it < 16; ++it) {
        int a = (it << 2) + (t >> 6);
        int b = t & 63;
        Ast[b][a] = A4[(i0 + a) * 64 + b];          // read coalesced in r
        Bsm[a][b] = B4[a * 4096 + j0 + b];          // read coalesced in j
    }
    __syncthreads();
    const int i = t & 63;
    const int jb = t >> 6;  // 0..3, uniform per wave -> Bsm broadcast
    float accv[16];
#pragma unroll
    for (int u = 0; u < 16; ++u) accv[u] = 0.f;
    for (int r = 0; r < 64; ++r) {
        float a = Ast[r][i];
#pragma unroll
        for (int u = 0; u < 16; ++u)
            accv[u] += a * Bsm[r][(jb << 4) + u];
    }
#pragma unroll
    for (int u = 0; u < 16; ++u)
        Wt[(j0 + (jb << 4) + u) * 4096 + i0 + i] = f2bf(accv[u]);
}

// ---------------- main GEMM: C = A(8192x4096) * Wt^T + bias -----------------
#define BM 128
#define BN 128
#define BK 32

__global__ __launch_bounds__(256) void gemm_bias_kernel(
    const short* __restrict__ A,    // M x K bf16
    const short* __restrict__ Bt,   // N x K bf16 (= W transposed)
    const float* __restrict__ bias,
    float* __restrict__ C) {
    constexpr int K = 4096, N = 4096;
    __shared__ short As[BM * BK];   // 8 KB
    __shared__ short Bs[BN * BK];   // 8 KB

    const int tid  = threadIdx.x;
    const int wave = tid >> 6;
    const int lane = tid & 63;

    // XCD-aware bijective swizzle (2048 blocks, 2048 % 8 == 0)
    const int bid = blockIdx.x;
    const int wg  = (bid & 7) * 256 + (bid >> 3);
    const int m0 = (wg >> 5) * BM;
    const int n0 = (wg & 31) * BN;

    // staging: 16B chunks; 4 chunks per 32-elem (64B) LDS row
    const int c0i = tid;         // chunks 0..255   (rows 0..63)
    const int c1i = 256 + tid;   // chunks 256..511 (rows 64..127)
    const short* gA0 = A  + (m0 + (c0i >> 2)) * K + ((c0i & 3) << 3);
    const short* gA1 = A  + (m0 + (c1i >> 2)) * K + ((c1i & 3) << 3);
    const short* gB0 = Bt + (n0 + (c0i >> 2)) * K + ((c0i & 3) << 3);
    const short* gB1 = Bt + (n0 + (c1i >> 2)) * K + ((c1i & 3) << 3);
    short* lA0 = As + wave * 512;         // wave-uniform LDS bases
    short* lA1 = As + 2048 + wave * 512;
    short* lB0 = Bs + wave * 512;
    short* lB1 = Bs + 2048 + wave * 512;

    const int wr = (wave >> 1) << 6;   // wave row quadrant: 0 / 64
    const int wc = (wave & 1) << 6;    // wave col quadrant: 0 / 64
    const int r16 = lane & 15;
    const int kq  = (lane >> 4) << 3;  // k offset of this lane's fragment

    f32x4 acc[4][4] = {};

    for (int kt = 0; kt < K / BK; ++kt) {
        __builtin_amdgcn_global_load_lds((const __attribute__((address_space(1))) void*)gA0,
                                         (__attribute__((address_space(3))) void*)lA0, 16, 0, 0);
        __builtin_amdgcn_global_load_lds((const __attribute__((address_space(1))) void*)gA1,
                                         (__attribute__((address_space(3))) void*)lA1, 16, 0, 0);
        __builtin_amdgcn_global_load_lds((const __attribute__((address_space(1))) void*)gB0,
                                         (__attribute__((address_space(3))) void*)lB0, 16, 0, 0);
        __builtin_amdgcn_global_load_lds((const __attribute__((address_space(1))) void*)gB1,
                                         (__attribute__((address_space(3))) void*)lB1, 16, 0, 0);
        gA0 += BK; gA1 += BK; gB0 += BK; gB1 += BK;
        __syncthreads();

        short8 a[4], b[4];
#pragma unroll
        for (int f = 0; f < 4; ++f) {
            a[f] = *(const short8*)(As + (wr + f * 16 + r16) * BK + kq);
            b[f] = *(const short8*)(Bs + (wc + f * 16 + r16) * BK + kq);
        }
#pragma unroll
        for (int i = 0; i < 4; ++i)
#pragma unroll
            for (int j = 0; j < 4; ++j)
                acc[i][j] = __builtin_amdgcn_mfma_f32_16x16x32_bf16(
                    a[i], b[j], acc[i][j], 0, 0, 0);
        __syncthreads();
    }

    // epilogue: C/D layout col=lane&15, row=(lane>>4)*4+reg
    const int crow = m0 + wr + ((lane >> 4) << 2);
    const int ccol = n0 + wc + r16;
#pragma unroll
    for (int i = 0; i < 4; ++i) {
#pragma unroll
        for (int j = 0; j < 4; ++j) {
            const int r = crow + i * 16;
            const int c = ccol + j * 16;
            const float bz = bias[c];
#pragma unroll
            for (int u = 0; u < 4; ++u)
                C[(r + u) * N + c] = acc[i][j][u] + bz;
        }
    }
}

// ---------------------------------------------------------------------------
extern "C" void kernel_launch(void* const* d_in, const int* in_sizes, int n_in,
                              void* d_out, int out_size, void* d_ws, size_t ws_size,
                              hipStream_t stream) {
    const float* x    = (const float*)d_in[0];
    const float* c0   = (const float*)d_in[1];
    const float* c1   = (const float*)d_in[2];
    const float* c2   = (const float*)d_in[3];
    const float* c3   = (const float*)d_in[4];
    const float* c4   = (const float*)d_in[5];
    const float* c5   = (const float*)d_in[6];
    const float* c6   = (const float*)d_in[7];
    const float* c7   = (const float*)d_in[8];
    const float* bias = (const float*)d_in[9];
    float* out = (float*)d_out;

    char* ws = (char*)d_ws;
    short* xb = (short*)ws;                         // 8192*4096*2 = 64 MiB
    short* Wt = (short*)(ws + 67108864);            // 4096*4096*2 = 32 MiB
    float* A2 = (float*)(ws + 100663296);           // 64*64
    float* A3 = A2 + 64 * 64;                       // 512*64
    float* A4 = A3 + 512 * 64;                      // 4096*64
    float* B6 = A4 + 4096 * 64;                     // 64*64
    float* B5 = B6 + 64 * 64;                       // 64*512
    float* B4 = B5 + 64 * 512;                      // 64*4096

    cast_x_kernel<<<2048, 256, 0, stream>>>(x, xb);

    tt_a_step<<<64, 64, 0, stream>>>(c0, c1, A2);      // (8,64)  -> (64,64)
    tt_a_step<<<512, 64, 0, stream>>>(A2, c2, A3);     // (64,64) -> (512,64)
    tt_a_step<<<4096, 64, 0, stream>>>(A3, c3, A4);    // (512,64)-> (4096,64)

    tt_b_step<<<512, 256, 0, stream>>>(c7, c6, B6, 8);    // (64,8)  -> (64,64)
    tt_b_step<<<512, 256, 0, stream>>>(B6, c5, B5, 64);   // (64,64) -> (64,512)
    tt_b_step<<<512, 256, 0, stream>>>(B5, c4, B4, 512);  // (64,512)-> (64,4096)

    build_wt_kernel<<<4096, 256, 0, stream>>>(A4, B4, Wt);

    gemm_bias_kernel<<<2048, 256, 0, stream>>>(xb, Wt, bias, out);
}

// Round 2
// 155.185 us; speedup vs baseline: 2.7918x; 2.7918x over previous
//
#include <hip/hip_runtime.h>
#include <hip/hip_bf16.h>

// ---------------------------------------------------------------------------
// TT-linear, rank-64 factorized:
//   W = A4(4096x64) . B4(64x4096)  =>  out = (x_pad @ A4) @ B4 + bias
//   GEMM1: z = x @ A4    (8192 x 64, K=4000, split-K by 8 -> zc 8192x512 bf16)
//   GEMM2: out = zc @ B2t^T + bias (K=512, B4 replicated 8x along K)
// 8.6 GFLOP total (vs 274 for the dense-W route); both GEMMs memory-bound.
// ---------------------------------------------------------------------------

typedef __attribute__((ext_vector_type(8))) short short8;
typedef __attribute__((ext_vector_type(4))) float f32x4;

__device__ __forceinline__ short f2bf(float f) {
    union { float f; unsigned u; } c; c.f = f;
    unsigned u = c.u;
    unsigned r = (u + 0x7fffu + ((u >> 16) & 1u)) >> 16;  // RNE
    return (short)r;
}

// ---------------- A-side chain step (verified round 1) ----------------------
// out[(i*8+d)][s] = sum_r in[i][r] * core[(r*8+d)*64 + s]
__global__ void tt_a_step(const float* __restrict__ in,
                          const float* __restrict__ core,
                          float* __restrict__ out) {
    const int row = blockIdx.x;
    const int i = row >> 3, d = row & 7;
    const int s = threadIdx.x;
    float acc = 0.f;
    for (int r = 0; r < 64; ++r)
        acc += in[i * 64 + r] * core[(r * 8 + d) * 64 + s];
    out[row * 64 + s] = acc;
}

// ---------------- B-side chain step (verified round 1) ----------------------
// out[r][d*Wj + j] = sum_q core[(r*8+d)*64 + q] * in[q*Wj + j]
__global__ void tt_b_step(const float* __restrict__ in,
                          const float* __restrict__ core,
                          float* __restrict__ out, int Wj) {
    const int rd = blockIdx.x;
    const int r = rd >> 3, d = rd & 7;
    for (int j = threadIdx.x; j < Wj; j += 256) {
        float acc = 0.f;
        for (int q = 0; q < 64; ++q)
            acc += core[(r * 8 + d) * 64 + q] * in[q * Wj + j];
        out[r * (8 * Wj) + d * Wj + j] = acc;
    }
}

// ---------------- A4 (4096x64 f32) -> A4t (64x4096 bf16, k-contiguous) ------
__global__ __launch_bounds__(256) void a4t_cast(const float* __restrict__ A4,
                                                short* __restrict__ A4t) {
    int idx = blockIdx.x * 256 + threadIdx.x;  // 64*4096
    int r = idx >> 12, k = idx & 4095;
    A4t[idx] = f2bf(A4[k * 64 + r]);
    (void)r;
}

// ---------------- B4 (64x4096 f32) -> B2t (4096x512 bf16, K-replicated) -----
// B2t[j][s*64+r] = B4[r][j]  (8 replicas so GEMM2 sums the 8 split-K partials)
__global__ __launch_bounds__(256) void b2t_build(const float* __restrict__ B4,
                                                 short* __restrict__ B2t) {
    int idx = blockIdx.x * 256 + threadIdx.x;  // 4096*512
    int j = idx >> 9, sk = idx & 511;
    B2t[idx] = f2bf(B4[(sk & 63) * 4096 + j]);
}

// ---------------- GEMM1: zc[b][ks*64+r] = sum_{k in split ks} x[b][k]A4[k][r]
// grid = 128 mblocks x 8 ksplits, 256 threads (4 waves x 16 rows each).
// x is 8192x4000 f32 (pad region is zero-contribution: 4000 = 125*32 tiles).
__global__ __launch_bounds__(256) void gemm1_kernel(
    const float* __restrict__ x, const short* __restrict__ A4t,
    short* __restrict__ zc) {
    const int tid = threadIdx.x, wave = tid >> 6, lane = tid & 63;
    const int mb = blockIdx.x >> 3, ks = blockIdx.x & 7;
    const int m0 = mb * 64 + wave * 16;
    const int kt0 = (ks * 125) >> 3, kt1 = ((ks + 1) * 125) >> 3;
    const int r16 = lane & 15, kq = (lane >> 4) << 3;
    const float* xp = x + (long)(m0 + r16) * 4000 + kq;

    f32x4 acc[4] = {};
    for (int t = kt0; t < kt1; ++t) {
        const int k0 = t << 5;
        f32x4 u0 = *(const f32x4*)(xp + k0);
        f32x4 u1 = *(const f32x4*)(xp + k0 + 4);
        short8 a;
        a[0] = f2bf(u0[0]); a[1] = f2bf(u0[1]);
        a[2] = f2bf(u0[2]); a[3] = f2bf(u0[3]);
        a[4] = f2bf(u1[0]); a[5] = f2bf(u1[1]);
        a[6] = f2bf(u1[2]); a[7] = f2bf(u1[3]);
#pragma unroll
        for (int f = 0; f < 4; ++f) {
            short8 b = *(const short8*)(A4t + (f * 16 + r16) * 4096 + k0 + kq);
            acc[f] = __builtin_amdgcn_mfma_f32_16x16x32_bf16(a, b, acc[f], 0, 0, 0);
        }
    }
    // C/D layout: col = lane&15 (+f*16), row = (lane>>4)*4 + u
    const int zr = m0 + ((lane >> 4) << 2);
#pragma unroll
    for (int f = 0; f < 4; ++f) {
        const int c = ks * 64 + f * 16 + r16;
#pragma unroll
        for (int u = 0; u < 4; ++u)
            zc[(zr + u) * 512 + c] = f2bf(acc[f][u]);
    }
}

// ---------------- GEMM2: C = zc(8192xK) * B2t(4096xK)^T + bias --------------
#define BM 128
#define BN 128
#define BK 32

template <int K>
__global__ __launch_bounds__(256) void gemm_bias_kernel(
    const short* __restrict__ A,    // M x K bf16
    const short* __restrict__ Bt,   // N x K bf16
    const float* __restrict__ bias,
    float* __restrict__ C) {
    constexpr int N = 4096;
    __shared__ short As[BM * BK];
    __shared__ short Bs[BN * BK];

    const int tid  = threadIdx.x;
    const int wave = tid >> 6;
    const int lane = tid & 63;

    const int bid = blockIdx.x;
    const int wg  = (bid & 7) * 256 + (bid >> 3);  // 2048 % 8 == 0, bijective
    const int m0 = (wg >> 5) * BM;
    const int n0 = (wg & 31) * BN;

    const int c0i = tid;
    const int c1i = 256 + tid;
    const short* gA0 = A  + (m0 + (c0i >> 2)) * K + ((c0i & 3) << 3);
    const short* gA1 = A  + (m0 + (c1i >> 2)) * K + ((c1i & 3) << 3);
    const short* gB0 = Bt + (n0 + (c0i >> 2)) * K + ((c0i & 3) << 3);
    const short* gB1 = Bt + (n0 + (c1i >> 2)) * K + ((c1i & 3) << 3);
    short* lA0 = As + wave * 512;
    short* lA1 = As + 2048 + wave * 512;
    short* lB0 = Bs + wave * 512;
    short* lB1 = Bs + 2048 + wave * 512;

    const int wr = (wave >> 1) << 6;
    const int wc = (wave & 1) << 6;
    const int r16 = lane & 15;
    const int kq  = (lane >> 4) << 3;

    f32x4 acc[4][4] = {};

    for (int kt = 0; kt < K / BK; ++kt) {
        __builtin_amdgcn_global_load_lds((const __attribute__((address_space(1))) void*)gA0,
                                         (__attribute__((address_space(3))) void*)lA0, 16, 0, 0);
        __builtin_amdgcn_global_load_lds((const __attribute__((address_space(1))) void*)gA1,
                                         (__attribute__((address_space(3))) void*)lA1, 16, 0, 0);
        __builtin_amdgcn_global_load_lds((const __attribute__((address_space(1))) void*)gB0,
                                         (__attribute__((address_space(3))) void*)lB0, 16, 0, 0);
        __builtin_amdgcn_global_load_lds((const __attribute__((address_space(1))) void*)gB1,
                                         (__attribute__((address_space(3))) void*)lB1, 16, 0, 0);
        gA0 += BK; gA1 += BK; gB0 += BK; gB1 += BK;
        __syncthreads();

        short8 a[4], b[4];
#pragma unroll
        for (int f = 0; f < 4; ++f) {
            a[f] = *(const short8*)(As + (wr + f * 16 + r16) * BK + kq);
            b[f] = *(const short8*)(Bs + (wc + f * 16 + r16) * BK + kq);
        }
#pragma unroll
        for (int i = 0; i < 4; ++i)
#pragma unroll
            for (int j = 0; j < 4; ++j)
                acc[i][j] = __builtin_amdgcn_mfma_f32_16x16x32_bf16(
                    a[i], b[j], acc[i][j], 0, 0, 0);
        __syncthreads();
    }

    const int crow = m0 + wr + ((lane >> 4) << 2);
    const int ccol = n0 + wc + r16;
#pragma unroll
    for (int i = 0; i < 4; ++i) {
#pragma unroll
        for (int j = 0; j < 4; ++j) {
            const int r = crow + i * 16;
            const int c = ccol + j * 16;
            const float bz = bias[c];
#pragma unroll
            for (int u = 0; u < 4; ++u)
                C[(r + u) * N + c] = acc[i][j][u] + bz;
        }
    }
}

// ---------------------------------------------------------------------------
extern "C" void kernel_launch(void* const* d_in, const int* in_sizes, int n_in,
                              void* d_out, int out_size, void* d_ws, size_t ws_size,
                              hipStream_t stream) {
    const float* x    = (const float*)d_in[0];
    const float* c0   = (const float*)d_in[1];
    const float* c1   = (const float*)d_in[2];
    const float* c2   = (const float*)d_in[3];
    const float* c3   = (const float*)d_in[4];
    const float* c4   = (const float*)d_in[5];
    const float* c5   = (const float*)d_in[6];
    const float* c6   = (const float*)d_in[7];
    const float* c7   = (const float*)d_in[8];
    const float* bias = (const float*)d_in[9];
    float* out = (float*)d_out;

    char* ws = (char*)d_ws;
    short* zc  = (short*)ws;                       // 8192*512*2  = 8 MiB
    short* B2t = (short*)(ws + (8u << 20));        // 4096*512*2  = 4 MiB
    short* A4t = (short*)(ws + (12u << 20));       // 64*4096*2   = 512 KiB
    float* A2 = (float*)(ws + (13u << 20));        // 64*64
    float* A3 = A2 + 64 * 64;                      // 512*64
    float* A4 = A3 + 512 * 64;                     // 4096*64 (1 MiB)
    float* B6 = A4 + 4096 * 64;                    // 64*64
    float* B5 = B6 + 64 * 64;                      // 64*512
    float* B4 = B5 + 64 * 512;                     // 64*4096 (1 MiB)

    // core chains (fp32, exact)
    tt_a_step<<<64, 64, 0, stream>>>(c0, c1, A2);      // (8,64)  -> (64,64)
    tt_a_step<<<512, 64, 0, stream>>>(A2, c2, A3);     // (64,64) -> (512,64)
    tt_a_step<<<4096, 64, 0, stream>>>(A3, c3, A4);    // (512,64)-> (4096,64)
    a4t_cast<<<1024, 256, 0, stream>>>(A4, A4t);

    tt_b_step<<<512, 256, 0, stream>>>(c7, c6, B6, 8);    // (64,8)  -> (64,64)
    tt_b_step<<<512, 256, 0, stream>>>(B6, c5, B5, 64);   // (64,64) -> (64,512)
    tt_b_step<<<512, 256, 0, stream>>>(B5, c4, B4, 512);  // (64,512)-> (64,4096)
    b2t_build<<<8192, 256, 0, stream>>>(B4, B2t);

    gemm1_kernel<<<1024, 256, 0, stream>>>(x, A4t, zc);
    gemm_bias_kernel<512><<<2048, 256, 0, stream>>>(zc, B2t, bias, out);
}